// Round 1
// baseline (333.852 us; speedup 1.0000x reference)
//
#include <hip/hip_runtime.h>
#include <stdint.h>

typedef __attribute__((ext_vector_type(4))) float f32x4;
typedef __attribute__((ext_vector_type(8))) short bf16x8;

static __device__ __forceinline__ unsigned short f2bf(float x) {
  unsigned int u = __builtin_bit_cast(unsigned int, x);
  u = (u + 0x7fffu + ((u >> 16) & 1u)) >> 16;
  return (unsigned short)u;
}

#define GLD16(g, l)                                                            \
  __builtin_amdgcn_global_load_lds(                                            \
      (__attribute__((address_space(1))) const void*)(g),                      \
      (__attribute__((address_space(3))) void*)(l), 16, 0, 0)

// ---------------- dinv = rsqrt(rowsum(graph)) : one wave per row -----------
__global__ __launch_bounds__(256) void row_rsqrt_k(const float* __restrict__ g,
                                                   float* __restrict__ dinv) {
  int row = blockIdx.x * 4 + (threadIdx.x >> 6);
  int lane = threadIdx.x & 63;
  const float* p = g + (long)row * 2048;
  float s = 0.f;
#pragma unroll
  for (int i = 0; i < 8; ++i) {
    float4 v = *(const float4*)(p + (lane + i * 64) * 4);
    s += v.x + v.y + v.z + v.w;
  }
#pragma unroll
  for (int off = 32; off; off >>= 1) s += __shfl_xor(s, off, 64);
  if (lane == 0) dinv[row] = rsqrtf(s);
}

// ---------------- weights f32 -> bf16 --------------------------------------
__global__ __launch_bounds__(256) void cvt_w_k(const float* __restrict__ W1,
                                               const float* __restrict__ W2,
                                               const float* __restrict__ Wout,
                                               unsigned short* __restrict__ wb) {
  int idx = blockIdx.x * 256 + threadIdx.x;  // 262144 total
  float v;
  if (idx < 65536) v = W1[idx];
  else if (idx < 131072) v = W2[idx - 65536];
  else v = Wout[idx - 131072];
  wb[idx] = f2bf(v);
}

// ---------------- node prep: agg[:, :256] = bf16(node); nodeT = (dinv*node)^T
__global__ __launch_bounds__(256) void prep_node_k(
    const float* __restrict__ node, const float* __restrict__ dinv,
    unsigned short* __restrict__ nodeT, unsigned short* __restrict__ agg) {
  __shared__ unsigned short t[64 * 68];
  int tid = threadIdx.x;
  int m0 = blockIdx.x * 64, h0 = blockIdx.y * 64;
  long b = blockIdx.z;
#pragma unroll
  for (int i = 0; i < 4; ++i) {
    int idx = tid + 256 * i;
    int r = idx >> 4, c4 = idx & 15;
    long m = m0 + r;
    float4 v = *(const float4*)(node + (b * 2048 + m) * 256 + h0 + c4 * 4);
    float di = dinv[b * 2048 + m];
    ushort4 u;
    u.x = f2bf(v.x); u.y = f2bf(v.y); u.z = f2bf(v.z); u.w = f2bf(v.w);
    *(ushort4*)(agg + (b * 2048 + m) * 512 + h0 + c4 * 4) = u;
    t[(c4 * 4 + 0) * 68 + r] = f2bf(v.x * di);
    t[(c4 * 4 + 1) * 68 + r] = f2bf(v.y * di);
    t[(c4 * 4 + 2) * 68 + r] = f2bf(v.z * di);
    t[(c4 * 4 + 3) * 68 + r] = f2bf(v.w * di);
  }
  __syncthreads();
#pragma unroll
  for (int i = 0; i < 4; ++i) {
    int idx = tid + 256 * i;
    int hr = idx >> 4, c4 = idx & 15;
    ushort4 o = *(const ushort4*)(&t[hr * 68 + c4 * 4]);
    *(ushort4*)(nodeT + (b * 256 + h0 + hr) * 2048 + m0 + c4 * 4) = o;
  }
}

// ---------------- GEMM: C[M,256] = A[M,K] @ Bt[256,K]^T ---------------------
// Block: 64 rows x 256 cols, 4 waves (each 64x64), BK=64, double-buffered LDS.
// A either f32 (reg-staged convert) or bf16 (global_load_lds, swizzled src).
// Bt always bf16 via global_load_lds with swizzled source.
// LDS XOR swizzle: byte = natural ^ ((row&7)<<4)  (T2-style, b128 reads clean)
template <bool A_BF16, bool BIAS, bool RELU, bool SCALE, bool TRANS, bool OUTF32>
__global__ __launch_bounds__(256) void gemm_bt(
    const void* __restrict__ Ap, const unsigned short* __restrict__ Bt,
    const float* __restrict__ bias, const float* __restrict__ scale,
    void* __restrict__ Cp, int K, long aBatch, long btBatch, long cBatch,
    int lda, int ldbt, int ldc) {
  __shared__ char lds[81920];  // A: 2x8192 @0, B: 2x32768 @16384
  char* ldsA = lds;
  char* ldsB = lds + 16384;

  int tid = threadIdx.x;
  int lane = tid & 63;
  int w = tid >> 6;

  // XCD-bijective swizzle: 256 blocks, batch = fid&7 -> one batch per XCD
  int fid = blockIdx.y * gridDim.x + blockIdx.x;
  int batch = fid & 7;
  int tile = fid >> 3;
  int bm0 = tile * 64;

  const float* Af32 = (const float*)Ap + (A_BF16 ? 0 : (long)batch * aBatch);
  const unsigned short* Abf =
      (const unsigned short*)Ap + (A_BF16 ? (long)batch * aBatch : 0);
  const unsigned short* Bb = Bt + (long)batch * btBatch;

  int nt = K >> 6;

  f32x4 acc[4][4] = {};
  float4 areg[4];

  auto stageB = [&](int kt, int buf) {
    char* base = ldsB + buf * 32768;
#pragma unroll
    for (int i = 0; i < 8; ++i) {
      int slot = (w * 8 + i) * 64 + lane;
      int c = slot >> 3, j = slot & 7;
      int jg = j ^ (c & 7);
      const unsigned short* src = Bb + (long)c * ldbt + kt * 64 + jg * 8;
      GLD16(src, base + (w * 8 + i) * 1024);
    }
  };
  auto stageA_lds = [&](int kt, int buf) {
    char* base = ldsA + buf * 8192;
#pragma unroll
    for (int i = 0; i < 2; ++i) {
      int slot = (w * 2 + i) * 64 + lane;
      int r = slot >> 3, j = slot & 7;
      int jg = j ^ (r & 7);
      const unsigned short* src = Abf + (long)(bm0 + r) * lda + kt * 64 + jg * 8;
      GLD16(src, base + (w * 2 + i) * 1024);
    }
  };
  auto loadA_regs = [&](int kt) {
#pragma unroll
    for (int i = 0; i < 4; ++i) {
      int idx = tid + 256 * i;
      int r = idx >> 4, c4 = idx & 15;
      areg[i] = *(const float4*)(Af32 + (long)(bm0 + r) * lda + kt * 64 + c4 * 4);
    }
  };
  auto writeA = [&](int buf) {
    char* base = ldsA + buf * 8192;
#pragma unroll
    for (int i = 0; i < 4; ++i) {
      int idx = tid + 256 * i;
      int r = idx >> 4, c4 = idx & 15;
      ushort4 h;
      h.x = f2bf(areg[i].x); h.y = f2bf(areg[i].y);
      h.z = f2bf(areg[i].z); h.w = f2bf(areg[i].w);
      int off = (r * 128 + c4 * 8) ^ ((r & 7) << 4);
      *(ushort4*)(base + off) = h;
    }
  };
  auto compute = [&](int buf) {
    char* bA = ldsA + buf * 8192;
    char* bB = ldsB + buf * 32768;
    bf16x8 a[4][2], bb[4][2];
#pragma unroll
    for (int m = 0; m < 4; ++m)
#pragma unroll
      for (int kk = 0; kk < 2; ++kk) {
        int row = m * 16 + (lane & 15);
        int off = (row * 128 + kk * 64 + (lane >> 4) * 16) ^ ((row & 7) << 4);
        a[m][kk] = *(const bf16x8*)(bA + off);
      }
#pragma unroll
    for (int n = 0; n < 4; ++n)
#pragma unroll
      for (int kk = 0; kk < 2; ++kk) {
        int col = w * 64 + n * 16 + (lane & 15);
        int off = (col * 128 + kk * 64 + (lane >> 4) * 16) ^ ((col & 7) << 4);
        bb[n][kk] = *(const bf16x8*)(bB + off);
      }
#pragma unroll
    for (int m = 0; m < 4; ++m)
#pragma unroll
      for (int n = 0; n < 4; ++n) {
        acc[m][n] = __builtin_amdgcn_mfma_f32_16x16x32_bf16(a[m][0], bb[n][0],
                                                            acc[m][n], 0, 0, 0);
        acc[m][n] = __builtin_amdgcn_mfma_f32_16x16x32_bf16(a[m][1], bb[n][1],
                                                            acc[m][n], 0, 0, 0);
      }
  };

  // prologue
  if (A_BF16) stageA_lds(0, 0);
  else { loadA_regs(0); writeA(0); }
  stageB(0, 0);
  __syncthreads();

  int cur = 0;
  for (int t = 0; t < nt; ++t) {
    int nxt = cur ^ 1;
    bool pf = (t + 1 < nt);
    if (pf) {
      if (A_BF16) stageA_lds(t + 1, nxt);
      else loadA_regs(t + 1);
      stageB(t + 1, nxt);
    }
    compute(cur);
    if (pf && !A_BF16) writeA(nxt);
    __syncthreads();
    cur = nxt;
  }

  // epilogue: C/D layout col=lane&15, row=(lane>>4)*4+reg (m89-verified)
#pragma unroll
  for (int m = 0; m < 4; ++m) {
#pragma unroll
    for (int n = 0; n < 4; ++n) {
      int col = w * 64 + n * 16 + (lane & 15);
      float bv = BIAS ? bias[col] : 0.f;
#pragma unroll
      for (int r = 0; r < 4; ++r) {
        int row = m * 16 + (lane >> 4) * 4 + r;
        float v = acc[m][n][r];
        if (BIAS) v += bv;
        if (RELU) v = fmaxf(v, 0.f);
        if (SCALE) v *= scale[(long)batch * 2048 + bm0 + row];
        if (OUTF32) {
          float* C = (float*)Cp + (long)batch * cBatch;
          C[(long)(bm0 + row) * ldc + col] = v;
        } else {
          unsigned short* C = (unsigned short*)Cp + (long)batch * cBatch;
          if (TRANS) C[(long)col * ldc + (bm0 + row)] = f2bf(v);
          else C[(long)(bm0 + row) * ldc + col] = f2bf(v);
        }
      }
    }
  }
}

extern "C" void kernel_launch(void* const* d_in, const int* in_sizes, int n_in,
                              void* d_out, int out_size, void* d_ws,
                              size_t ws_size, hipStream_t stream) {
  const float* node = (const float*)d_in[0];   // [8,2048,256]
  const float* graph = (const float*)d_in[1];  // [8,2048,2048]
  const float* W1 = (const float*)d_in[2];     // [256,256]
  const float* b1 = (const float*)d_in[3];
  const float* W2 = (const float*)d_in[4];
  const float* b2 = (const float*)d_in[5];
  const float* Wout = (const float*)d_in[6];   // [256,512]
  const float* bout = (const float*)d_in[7];
  float* out = (float*)d_out;

  char* p = (char*)d_ws;
  float* dinv = (float*)p;              p += 16384 * 4;        // 64KB
  unsigned short* wb = (unsigned short*)p; p += 262144 * 2;    // W1b|W2b|Woutb
  unsigned short* nodeT = (unsigned short*)p; p += 8L * 256 * 2048 * 2; // also X1T
  unsigned short* bufT = (unsigned short*)p;  p += 8L * 2048 * 256 * 2; // A1/A2
  unsigned short* agg = (unsigned short*)p;   p += 8L * 2048 * 512 * 2;

  row_rsqrt_k<<<4096, 256, 0, stream>>>(graph, dinv);
  cvt_w_k<<<1024, 256, 0, stream>>>(W1, W2, Wout, wb);
  prep_node_k<<<dim3(32, 4, 8), 256, 0, stream>>>(node, dinv, nodeT, agg);

  // G1: A1 = dinv .* (graph @ node_s)   -> bufT bf16 row-major
  gemm_bt<false, false, false, true, false, false>
      <<<dim3(32, 8), 256, 0, stream>>>(graph, nodeT, nullptr, dinv, bufT, 2048,
                                        2048L * 2048, 256L * 2048, 2048L * 256,
                                        2048, 2048, 256);
  // F1: X1s^T = (dinv .* relu(A1 @ W1^T + b1))^T  -> nodeT buffer
  gemm_bt<true, true, true, true, true, false>
      <<<dim3(32, 8), 256, 0, stream>>>(bufT, wb, b1, dinv, nodeT, 256,
                                        2048L * 256, 0, 256L * 2048,
                                        256, 256, 2048);
  // G2: A2 = dinv .* (graph @ X1s)  -> bufT
  gemm_bt<false, false, false, true, false, false>
      <<<dim3(32, 8), 256, 0, stream>>>(graph, nodeT, nullptr, dinv, bufT, 2048,
                                        2048L * 2048, 256L * 2048, 2048L * 256,
                                        2048, 2048, 256);
  // F2: X2 = relu(A2 @ W2^T + b2) -> agg[:, 256:512]
  gemm_bt<true, true, true, false, false, false>
      <<<dim3(32, 8), 256, 0, stream>>>(bufT, wb + 65536, b2, nullptr, agg + 256,
                                        256, 2048L * 256, 0, 2048L * 512,
                                        256, 256, 512);
  // F3: out = relu(agg @ Wout^T + bout)  (K=512, f32 out)
  gemm_bt<true, true, true, false, false, true>
      <<<dim3(32, 8), 256, 0, stream>>>(agg, wb + 131072, bout, nullptr, out,
                                        512, 2048L * 512, 0, 2048L * 256,
                                        512, 512, 256);
}

// Round 2
// 313.998 us; speedup vs baseline: 1.0632x; 1.0632x over previous
//
#include <hip/hip_runtime.h>
#include <stdint.h>

typedef __attribute__((ext_vector_type(4))) float f32x4;
typedef __attribute__((ext_vector_type(8))) short bf16x8;

static __device__ __forceinline__ unsigned short f2bf(float x) {
  unsigned int u = __builtin_bit_cast(unsigned int, x);
  u = (u + 0x7fffu + ((u >> 16) & 1u)) >> 16;
  return (unsigned short)u;
}

#define GLD16(g, l)                                                            \
  __builtin_amdgcn_global_load_lds(                                            \
      (__attribute__((address_space(1))) const void*)(g),                      \
      (__attribute__((address_space(3))) void*)(l), 16, 0, 0)

// ---- pass1: dinv = rsqrt(rowsum(graph)); gb = bf16(dinv[row] * graph) ------
__global__ __launch_bounds__(256) void rowscale_cvt_k(
    const float* __restrict__ g, float* __restrict__ dinv,
    unsigned short* __restrict__ gb) {
  int row = blockIdx.x * 4 + (threadIdx.x >> 6);
  int lane = threadIdx.x & 63;
  const float* p = g + (long)row * 2048;
  float4 v[8];
  float s = 0.f;
#pragma unroll
  for (int i = 0; i < 8; ++i) {
    v[i] = *(const float4*)(p + (lane + i * 64) * 4);
    s += v[i].x + v[i].y + v[i].z + v[i].w;
  }
#pragma unroll
  for (int off = 32; off; off >>= 1) s += __shfl_xor(s, off, 64);
  float di = rsqrtf(s);
  if (lane == 0) dinv[row] = di;
  unsigned short* q = gb + (long)row * 2048;
#pragma unroll
  for (int i = 0; i < 8; ++i) {
    ushort4 u;
    u.x = f2bf(v[i].x * di); u.y = f2bf(v[i].y * di);
    u.z = f2bf(v[i].z * di); u.w = f2bf(v[i].w * di);
    *(ushort4*)(q + (lane + i * 64) * 4) = u;
  }
}

// ---- weights f32 -> bf16 ---------------------------------------------------
__global__ __launch_bounds__(256) void cvt_w_k(const float* __restrict__ W1,
                                               const float* __restrict__ W2,
                                               const float* __restrict__ Wout,
                                               unsigned short* __restrict__ wb) {
  int idx = blockIdx.x * 256 + threadIdx.x;  // 262144 total
  float v;
  if (idx < 65536) v = W1[idx];
  else if (idx < 131072) v = W2[idx - 65536];
  else v = Wout[idx - 131072];
  wb[idx] = f2bf(v);
}

// ---- node prep: agg[:, :256] = bf16(node); nodeT = (dinv*node)^T -----------
__global__ __launch_bounds__(256) void prep_node_k(
    const float* __restrict__ node, const float* __restrict__ dinv,
    unsigned short* __restrict__ nodeT, unsigned short* __restrict__ agg) {
  __shared__ unsigned short t[64 * 68];
  int tid = threadIdx.x;
  int m0 = blockIdx.x * 64, h0 = blockIdx.y * 64;
  long b = blockIdx.z;
#pragma unroll
  for (int i = 0; i < 4; ++i) {
    int idx = tid + 256 * i;
    int r = idx >> 4, c4 = idx & 15;
    long m = m0 + r;
    float4 v = *(const float4*)(node + (b * 2048 + m) * 256 + h0 + c4 * 4);
    float di = dinv[b * 2048 + m];
    ushort4 u;
    u.x = f2bf(v.x); u.y = f2bf(v.y); u.z = f2bf(v.z); u.w = f2bf(v.w);
    *(ushort4*)(agg + (b * 2048 + m) * 512 + h0 + c4 * 4) = u;
    t[(c4 * 4 + 0) * 68 + r] = f2bf(v.x * di);
    t[(c4 * 4 + 1) * 68 + r] = f2bf(v.y * di);
    t[(c4 * 4 + 2) * 68 + r] = f2bf(v.z * di);
    t[(c4 * 4 + 3) * 68 + r] = f2bf(v.w * di);
  }
  __syncthreads();
#pragma unroll
  for (int i = 0; i < 4; ++i) {
    int idx = tid + 256 * i;
    int hr = idx >> 4, c4 = idx & 15;
    ushort4 o = *(const ushort4*)(&t[hr * 68 + c4 * 4]);
    *(ushort4*)(nodeT + (b * 256 + h0 + hr) * 2048 + m0 + c4 * 4) = o;
  }
}

// ---- GEMM: C[32,256] per block = A[32,K] @ Bt[256,K]^T ---------------------
// 4 waves, each 32x64. BK=64, double-buffered LDS (72KB -> 2 blocks/CU).
// All operands bf16 via global_load_lds w=16, XOR-swizzled source (T2/m173).
template <bool BIAS, bool RELU, bool SCALE, bool TRANS, bool OUTF32>
__global__ __launch_bounds__(256) void gemm32(
    const unsigned short* __restrict__ A, const unsigned short* __restrict__ Bt,
    const float* __restrict__ bias, const float* __restrict__ scale,
    void* __restrict__ Cp, int K, int lda, int ldbt, long bBatch, int ldc) {
  __shared__ char lds[73728];  // A: 2x4096 @0, B: 2x32768 @8192
  char* ldsA = lds;
  char* ldsB = lds + 8192;

  int tid = threadIdx.x;
  int lane = tid & 63;
  int w = tid >> 6;

  // XCD-bijective swizzle: 512 blocks, 64 consecutive tiles (one batch) / XCD
  int bid = blockIdx.x;
  int tile = ((bid & 7) << 6) + (bid >> 3);
  int row0 = tile * 32;
  int batch = row0 >> 11;
  const unsigned short* Bb = Bt + (long)batch * bBatch;

  int nt = K >> 6;
  f32x4 acc[2][4] = {};

  auto stageA = [&](int kt, int buf) {
    int slot = w * 64 + lane;
    int r = slot >> 3, j = slot & 7;
    int jg = j ^ (r & 7);
    GLD16(A + (long)(row0 + r) * lda + kt * 64 + jg * 8,
          ldsA + buf * 4096 + w * 1024);
  };
  auto stageB = [&](int kt, int buf) {
    char* base = ldsB + buf * 32768;
#pragma unroll
    for (int i = 0; i < 8; ++i) {
      int slot = (w * 8 + i) * 64 + lane;
      int c = slot >> 3, j = slot & 7;
      int jg = j ^ (c & 7);
      GLD16(Bb + (long)c * ldbt + kt * 64 + jg * 8, base + (w * 8 + i) * 1024);
    }
  };
  auto compute = [&](int buf) {
    char* bA = ldsA + buf * 4096;
    char* bB = ldsB + buf * 32768;
    bf16x8 a[2][2], bb[4][2];
#pragma unroll
    for (int m = 0; m < 2; ++m)
#pragma unroll
      for (int kk = 0; kk < 2; ++kk) {
        int row = m * 16 + (lane & 15);
        int off = (row * 128 + kk * 64 + (lane >> 4) * 16) ^ ((row & 7) << 4);
        a[m][kk] = *(const bf16x8*)(bA + off);
      }
#pragma unroll
    for (int n = 0; n < 4; ++n)
#pragma unroll
      for (int kk = 0; kk < 2; ++kk) {
        int col = w * 64 + n * 16 + (lane & 15);
        int off = (col * 128 + kk * 64 + (lane >> 4) * 16) ^ ((col & 7) << 4);
        bb[n][kk] = *(const bf16x8*)(bB + off);
      }
#pragma unroll
    for (int m = 0; m < 2; ++m)
#pragma unroll
      for (int n = 0; n < 4; ++n) {
        acc[m][n] = __builtin_amdgcn_mfma_f32_16x16x32_bf16(a[m][0], bb[n][0],
                                                            acc[m][n], 0, 0, 0);
        acc[m][n] = __builtin_amdgcn_mfma_f32_16x16x32_bf16(a[m][1], bb[n][1],
                                                            acc[m][n], 0, 0, 0);
      }
  };

  stageA(0, 0);
  stageB(0, 0);
  __syncthreads();

  int cur = 0;
  for (int t = 0; t < nt; ++t) {
    int nxt = cur ^ 1;
    if (t + 1 < nt) {
      stageA(t + 1, nxt);
      stageB(t + 1, nxt);
    }
    compute(cur);
    __syncthreads();
    cur = nxt;
  }

  // epilogue: C/D layout col=lane&15, row=(lane>>4)*4+r (m89-verified)
  if (TRANS) {
    unsigned short* tb = (unsigned short*)lds;  // [256 cols][40] padded
#pragma unroll
    for (int m = 0; m < 2; ++m)
#pragma unroll
      for (int n = 0; n < 4; ++n) {
        int col = w * 64 + n * 16 + (lane & 15);
        float bv = BIAS ? bias[col] : 0.f;
#pragma unroll
        for (int r = 0; r < 4; ++r) {
          int rl = m * 16 + (lane >> 4) * 4 + r;
          float v = acc[m][n][r];
          if (BIAS) v += bv;
          if (RELU) v = fmaxf(v, 0.f);
          if (SCALE) v *= scale[row0 + rl];
          tb[col * 40 + rl] = f2bf(v);
        }
      }
    __syncthreads();
    unsigned short* C = (unsigned short*)Cp;
    int rin = row0 & 2047;
#pragma unroll
    for (int cc = 0; cc < 4; ++cc) {
      int col = (tid >> 2) + cc * 64;
      int seg = tid & 3;
      bf16x8 u = *(const bf16x8*)(tb + col * 40 + seg * 8);
      *(bf16x8*)(C + ((long)batch * 256 + col) * 2048 + rin + seg * 8) = u;
    }
  } else {
#pragma unroll
    for (int m = 0; m < 2; ++m)
#pragma unroll
      for (int n = 0; n < 4; ++n) {
        int col = w * 64 + n * 16 + (lane & 15);
        float bv = BIAS ? bias[col] : 0.f;
#pragma unroll
        for (int r = 0; r < 4; ++r) {
          long row = row0 + m * 16 + (lane >> 4) * 4 + r;
          float v = acc[m][n][r];
          if (BIAS) v += bv;
          if (RELU) v = fmaxf(v, 0.f);
          if (SCALE) v *= scale[row];
          if (OUTF32) ((float*)Cp)[row * ldc + col] = v;
          else ((unsigned short*)Cp)[row * ldc + col] = f2bf(v);
        }
      }
  }
}

extern "C" void kernel_launch(void* const* d_in, const int* in_sizes, int n_in,
                              void* d_out, int out_size, void* d_ws,
                              size_t ws_size, hipStream_t stream) {
  const float* node = (const float*)d_in[0];   // [8,2048,256]
  const float* graph = (const float*)d_in[1];  // [8,2048,2048]
  const float* W1 = (const float*)d_in[2];
  const float* b1 = (const float*)d_in[3];
  const float* W2 = (const float*)d_in[4];
  const float* b2 = (const float*)d_in[5];
  const float* Wout = (const float*)d_in[6];   // [256,512]
  const float* bout = (const float*)d_in[7];
  float* out = (float*)d_out;

  char* p = (char*)d_ws;
  float* dinv = (float*)p;                    p += 16384 * 4;
  unsigned short* wb = (unsigned short*)p;    p += 262144 * 2;
  unsigned short* gb = (unsigned short*)p;    p += 8L * 2048 * 2048 * 2;  // 64MB
  unsigned short* nodeT = (unsigned short*)p; p += 8L * 256 * 2048 * 2;  // /X1sT
  unsigned short* bufT = (unsigned short*)p;  p += 8L * 2048 * 256 * 2;  // A1/A2
  unsigned short* agg = (unsigned short*)p;   p += 8L * 2048 * 512 * 2;

  // 1. dinv + scaled bf16 graph (single f32 read of graph)
  rowscale_cvt_k<<<4096, 256, 0, stream>>>(graph, dinv, gb);
  cvt_w_k<<<1024, 256, 0, stream>>>(W1, W2, Wout, wb);
  prep_node_k<<<dim3(32, 4, 8), 256, 0, stream>>>(node, dinv, nodeT, agg);

  // G1: A1 = gb @ nodeT^T  (dinv_n in gb, dinv_m in nodeT)
  gemm32<false, false, false, false, false><<<512, 256, 0, stream>>>(
      gb, nodeT, nullptr, nullptr, bufT, 2048, 2048, 2048, 256L * 2048, 256);
  // F1: X1s^T = (dinv .* relu(A1 @ W1^T + b1))^T -> nodeT buffer
  gemm32<true, true, true, true, false><<<512, 256, 0, stream>>>(
      bufT, wb, b1, dinv, nodeT, 256, 256, 256, 0, 2048);
  // G2: A2 = gb @ X1s^T^T
  gemm32<false, false, false, false, false><<<512, 256, 0, stream>>>(
      gb, nodeT, nullptr, nullptr, bufT, 2048, 2048, 2048, 256L * 2048, 256);
  // F2: X2 = relu(A2 @ W2^T + b2) -> agg[:, 256:512]
  gemm32<true, true, false, false, false><<<512, 256, 0, stream>>>(
      bufT, wb + 65536, b2, nullptr, agg + 256, 256, 256, 256, 0, 512);
  // F3: out = relu(agg @ Wout^T + bout)  (K=512, f32 out)
  gemm32<true, true, false, false, true><<<512, 256, 0, stream>>>(
      agg, wb + 131072, bout, nullptr, out, 512, 512, 512, 0, 256);
}